// Round 9
// baseline (282.579 us; speedup 1.0000x reference)
//
#include <hip/hip_runtime.h>
#include <hip/hip_bf16.h>
#include <math.h>

typedef __attribute__((ext_vector_type(8))) short bf16x8;
typedef __attribute__((ext_vector_type(4))) float f32x4;

#define N_B  2
#define CIN  128
#define COUT 128
#define T_   16
#define H_   64
#define W_   64
#define FANIN 3456

// ---- workspace byte offsets ----
#define OFF_WMAX   0          // 128 f32
#define OFF_SMAX   512        // 2 f32
#define OFF_SNORM  1024       // 4096 f32
#define OFF_WSQ    20480      // 16384 f32
#define OFF_DEMOD  86016      // 4096 f32
#define OFF_APACK  102400     // 442368 ushort (884,736 B)  [tap27][c4][m8][lane64][j8]
#define OFF_XMT    2097152    // 16,777,216 ushort (33.55 MB) [n][t][h][w][cin] bf16

// ---------- prep kernels ----------
__global__ __launch_bounds__(256) void k_wmax(const float* __restrict__ w,
                                              float* __restrict__ wmax) {
    int o = blockIdx.x;
    const float* p = w + (size_t)o * FANIN;
    float m = 0.f;
    for (int i = threadIdx.x; i < FANIN; i += 256) m = fmaxf(m, fabsf(p[i]));
    __shared__ float red[256];
    red[threadIdx.x] = m; __syncthreads();
    for (int s = 128; s > 0; s >>= 1) {
        if (threadIdx.x < s) red[threadIdx.x] = fmaxf(red[threadIdx.x], red[threadIdx.x + s]);
        __syncthreads();
    }
    if (threadIdx.x == 0) wmax[o] = red[0];
}

__global__ __launch_bounds__(256) void k_smax(const float* __restrict__ s,
                                              float* __restrict__ smax) {
    int n = blockIdx.x;
    const float* p = s + (size_t)n * CIN * T_;
    float m = 0.f;
    for (int i = threadIdx.x; i < CIN * T_; i += 256) m = fmaxf(m, fabsf(p[i]));
    __shared__ float red[256];
    red[threadIdx.x] = m; __syncthreads();
    for (int q = 128; q > 0; q >>= 1) {
        if (threadIdx.x < q) red[threadIdx.x] = fmaxf(red[threadIdx.x], red[threadIdx.x + q]);
        __syncthreads();
    }
    if (threadIdx.x == 0) smax[n] = red[0];
}

__global__ __launch_bounds__(256) void k_snorm(const float* __restrict__ style,
                                               const float* __restrict__ smax,
                                               float* __restrict__ snorm) {
    int idx = blockIdx.x * 256 + threadIdx.x;
    if (idx < N_B * CIN * T_) {
        int n = idx / (CIN * T_);
        snorm[idx] = style[idx] / smax[n];
    }
}

// normalize weight (fp32), pack bf16 into MFMA A-frag order, compute wsq[o][i]
__global__ __launch_bounds__(128) void k_wpack(const float* __restrict__ w,
                                               const float* __restrict__ wmax,
                                               ushort* __restrict__ apack,
                                               float* __restrict__ wsq) {
    int o = blockIdx.x, i = threadIdx.x;
    float inv = 1.0f / (wmax[o] * sqrtf((float)FANIN));
    const float* p = w + ((size_t)o * CIN + i) * 27;
    int c = i >> 5, ii = i & 31;
    int lane = (o & 15) + ((ii >> 3) << 4);   // A: row=l&15, k=(l>>4)*8+j
    int j = ii & 7;
    int m = o >> 4;
    size_t base = (((size_t)c * 8 + m) * 64 + lane) * 8 + j;
    float sq = 0.f;
    #pragma unroll
    for (int tap = 0; tap < 27; tap++) {
        float wn = p[tap] * inv;
        sq = fmaf(wn, wn, sq);
        __hip_bfloat16 hb = __float2bfloat16(wn);
        apack[base + (size_t)tap * 16384] = *(ushort*)&hb;
    }
    wsq[o * CIN + i] = sq;
}

__global__ __launch_bounds__(128) void k_demod(const float* __restrict__ wsq,
                                               const float* __restrict__ snorm,
                                               float* __restrict__ demod) {
    int nt = blockIdx.x;
    int n = nt / T_, t = nt % T_;
    __shared__ float s2[CIN];
    int tid = threadIdx.x;
    float sv = snorm[(n * CIN + tid) * T_ + t];
    s2[tid] = sv * sv;
    __syncthreads();
    const float* wq = wsq + tid * CIN;   // o = tid
    float d = 0.f;
    for (int i = 0; i < CIN; i++) d = fmaf(wq[i], s2[i], d);
    demod[(n * COUT + tid) * T_ + t] = 1.0f / sqrtf(d + 1e-8f);
}

// transpose x -> xmt[n][t][h][w][cin] bf16, style-modulated
__global__ __launch_bounds__(256) void k_xmt(const float* __restrict__ x,
                                             const float* __restrict__ snorm,
                                             ushort* __restrict__ xmt) {
    __shared__ float lds[CIN * 65];
    int bid = blockIdx.x;
    int h = bid & 63, t = (bid >> 6) & 15, n = bid >> 10;
    int tid = threadIdx.x;
    int wl = tid & 63, cq = tid >> 6;
    for (int pass = 0; pass < 32; pass++) {
        int ci = pass * 4 + cq;
        float s = snorm[(n * CIN + ci) * T_ + t];
        float v = x[(((size_t)(n * CIN + ci) * T_ + t) * H_ + h) * W_ + wl] * s;
        lds[ci * 65 + wl] = v;
    }
    __syncthreads();
    int ci2 = tid & 63, wq = tid >> 6;
    uint* dst = (uint*)xmt;
    for (int pass = 0; pass < 16; pass++) {
        int w = pass * 4 + wq;
        float f0 = lds[(2 * ci2) * 65 + w];
        float f1 = lds[(2 * ci2 + 1) * 65 + w];
        __hip_bfloat16 h0 = __float2bfloat16(f0);
        __hip_bfloat16 h1 = __float2bfloat16(f1);
        uint pk = (uint)(*(ushort*)&h0) | ((uint)(*(ushort*)&h1) << 16);
        dst[((((size_t)(n * T_ + t) * H_ + h) * W_ + w)) * 64 + ci2] = pk;
    }
}

// ---------- main MFMA conv ----------
// grid: 1024 blocks = n(2) * t(16) * h2(32); block = 256 thr = 4 waves
// block tile: 128 Cout x (2h x 64w); wave: 64 Cout x (1h x 64w)
// A-operand ping-pong pipeline (R6) + 3 blocks/CU via launch_bounds(256,3):
// independent blocks cover each other's stage windows (TLP, not ILP).
__global__ __launch_bounds__(256, 3) void k_conv(const ushort* __restrict__ xmt,
                                                 const ushort* __restrict__ apack,
                                                 const float* __restrict__ demod,
                                                 const float* __restrict__ bias,
                                                 float* __restrict__ out) {
    // xs[t'3][h'4][g4][w66] granules of 8 bf16 (16B); 50688 B -> 3 blocks/CU
    __shared__ ushort __attribute__((aligned(16))) xs[25344];

    int bid = blockIdx.x;
    int h2 = bid & 31, t = (bid >> 5) & 15, n = bid >> 9;
    int hbase = h2 * 2;
    int tid = threadIdx.x;
    int lane = tid & 63;
    int wid = tid >> 6;
    int mrow = wid & 1;    // cout half (64)
    int hrow = wid >> 1;   // h row (0/1)

    // ---- chunk-invariant staging offsets (13 granules/thread) ----
    uint goff[13];     // element offset into xmt (for chunk c add c*32)
    uint loff[13];     // byte offset into xs; 0xFFFFFFFF = no slot
    uint vmask = 0;    // bit k set -> in-bounds (load), clear -> zero-fill
    #pragma unroll
    for (int k = 0; k < 13; ++k) {
        int idx = tid + (k << 8);
        goff[k] = 0u;
        if (idx < 3168) {
            int g = idx & 3;
            int r = idx >> 2;
            int w = r % 66;
            int q = r / 66;
            int hh = q & 3, tz = q >> 2;
            int gt = t + tz - 1, gh = hbase + hh - 1, gw = w - 1;
            if ((unsigned)gt < T_ && (unsigned)gh < H_ && (unsigned)gw < W_) {
                goff[k] = (uint)((((n * T_ + gt) * H_ + gh) * W_ + gw) * CIN + g * 8);
                vmask |= (1u << k);
            }
            loff[k] = (uint)(((((tz * 4 + hh) * 4) + g) * 66 + w) * 16);
        } else {
            loff[k] = 0xFFFFFFFFu;
        }
    }

    f32x4 acc[4][4];
    #pragma unroll
    for (int i = 0; i < 4; i++)
        #pragma unroll
        for (int jn = 0; jn < 4; jn++)
            acc[i][jn] = (f32x4){0.f, 0.f, 0.f, 0.f};

    bf16x8 Abank0[12], Abank1[12];

#define LOADA(BANK, G) do { \
    const ushort* apg_ = apc + (G) * 3 * 16384; \
    _Pragma("unroll") \
    for (int dx_ = 0; dx_ < 3; ++dx_) { \
        _Pragma("unroll") \
        for (int mi_ = 0; mi_ < 4; ++mi_) \
            BANK[dx_ * 4 + mi_] = *(const bf16x8*)(apg_ + dx_ * 16384 + mi_ * 512); \
    } \
} while (0)

#define GROUPC(BANK, G) do { \
    const int tz_ = (G) / 3, dy_ = (G) % 3; \
    const ushort* bb_ = &xs[(((tz_ * 4 + hrow + dy_) * 4 + (lane >> 4)) * 66 + (lane & 15)) * 8]; \
    _Pragma("unroll") \
    for (int dx_ = 0; dx_ < 3; ++dx_) { \
        bf16x8 b0_ = *(const bf16x8*)(bb_ + dx_ * 8); \
        bf16x8 b1_ = *(const bf16x8*)(bb_ + dx_ * 8 + 128); \
        bf16x8 b2_ = *(const bf16x8*)(bb_ + dx_ * 8 + 256); \
        bf16x8 b3_ = *(const bf16x8*)(bb_ + dx_ * 8 + 384); \
        _Pragma("unroll") \
        for (int mi_ = 0; mi_ < 4; ++mi_) { \
            acc[mi_][0] = __builtin_amdgcn_mfma_f32_16x16x32_bf16(BANK[dx_*4+mi_], b0_, acc[mi_][0], 0, 0, 0); \
            acc[mi_][1] = __builtin_amdgcn_mfma_f32_16x16x32_bf16(BANK[dx_*4+mi_], b1_, acc[mi_][1], 0, 0, 0); \
            acc[mi_][2] = __builtin_amdgcn_mfma_f32_16x16x32_bf16(BANK[dx_*4+mi_], b2_, acc[mi_][2], 0, 0, 0); \
            acc[mi_][3] = __builtin_amdgcn_mfma_f32_16x16x32_bf16(BANK[dx_*4+mi_], b3_, acc[mi_][3], 0, 0, 0); \
        } \
    } \
} while (0)

    for (int c = 0; c < 4; ++c) {     // cin chunks of 32
        __syncthreads();   // waves done reading previous chunk
        // serial stage of chunk c: 13 loads then 13 ds_writes
        {
            uint4 pv[13];
            #pragma unroll
            for (int k = 0; k < 13; ++k) {
                uint4 v = make_uint4(0u, 0u, 0u, 0u);
                if ((vmask >> k) & 1u) v = *(const uint4*)(xmt + goff[k] + c * 32);
                pv[k] = v;
            }
            #pragma unroll
            for (int k = 0; k < 13; ++k)
                if (loff[k] != 0xFFFFFFFFu) *(uint4*)((char*)&xs[0] + loff[k]) = pv[k];
        }
        __syncthreads();

        const ushort* apc = apack + (c * 4096 + mrow * 2048 + lane * 8);

        LOADA(Abank0, 0);
        LOADA(Abank1, 1); __builtin_amdgcn_sched_barrier(0); GROUPC(Abank0, 0);
        LOADA(Abank0, 2); __builtin_amdgcn_sched_barrier(0); GROUPC(Abank1, 1);
        LOADA(Abank1, 3); __builtin_amdgcn_sched_barrier(0); GROUPC(Abank0, 2);
        LOADA(Abank0, 4); __builtin_amdgcn_sched_barrier(0); GROUPC(Abank1, 3);
        LOADA(Abank1, 5); __builtin_amdgcn_sched_barrier(0); GROUPC(Abank0, 4);
        LOADA(Abank0, 6); __builtin_amdgcn_sched_barrier(0); GROUPC(Abank1, 5);
        LOADA(Abank1, 7); __builtin_amdgcn_sched_barrier(0); GROUPC(Abank0, 6);
        LOADA(Abank0, 8); __builtin_amdgcn_sched_barrier(0); GROUPC(Abank1, 7);
        GROUPC(Abank0, 8);
    }
#undef LOADA
#undef GROUPC

    // epilogue: C layout col=lane&15 (w), row=(lane>>4)*4+reg (cout)
    int h = hbase + hrow;
    #pragma unroll
    for (int mi = 0; mi < 4; mi++) {
        #pragma unroll
        for (int r = 0; r < 4; r++) {
            int o = mrow * 64 + mi * 16 + (lane >> 4) * 4 + r;
            float d = demod[(n * COUT + o) * T_ + t];
            float bv = bias[o];
            #pragma unroll
            for (int nb = 0; nb < 4; nb++) {
                float z = fmaf(acc[mi][nb][r], d, bv);
                z = (z >= 0.f ? z : 0.2f * z) * 1.41421356237309515f;
                out[(((size_t)(n * COUT + o) * T_ + t) * H_ + h) * W_ + nb * 16 + (lane & 15)] = z;
            }
        }
    }
}

extern "C" void kernel_launch(void* const* d_in, const int* in_sizes, int n_in,
                              void* d_out, int out_size, void* d_ws, size_t ws_size,
                              hipStream_t stream) {
    const float* x      = (const float*)d_in[0];
    const float* weight = (const float*)d_in[1];
    const float* style  = (const float*)d_in[2];
    const float* bias   = (const float*)d_in[3];
    float* out = (float*)d_out;

    char* ws = (char*)d_ws;
    float*  wmax  = (float*)(ws + OFF_WMAX);
    float*  smax  = (float*)(ws + OFF_SMAX);
    float*  snorm = (float*)(ws + OFF_SNORM);
    float*  wsq   = (float*)(ws + OFF_WSQ);
    float*  demod = (float*)(ws + OFF_DEMOD);
    ushort* apack = (ushort*)(ws + OFF_APACK);
    ushort* xmt   = (ushort*)(ws + OFF_XMT);

    k_wmax <<<COUT, 256, 0, stream>>>(weight, wmax);
    k_smax <<<N_B, 256, 0, stream>>>(style, smax);
    k_snorm<<<(N_B * CIN * T_ + 255) / 256, 256, 0, stream>>>(style, smax, snorm);
    k_wpack<<<COUT, 128, 0, stream>>>(weight, wmax, apack, wsq);
    k_demod<<<N_B * T_, 128, 0, stream>>>(wsq, snorm, demod);
    k_xmt  <<<N_B * T_ * H_, 256, 0, stream>>>(x, snorm, xmt);

    k_conv<<<N_B * T_ * (H_ / 2), 256, 0, stream>>>(xmt, apack, demod, bias, out);
}

// Round 10
// 277.512 us; speedup vs baseline: 1.0183x; 1.0183x over previous
//
#include <hip/hip_runtime.h>
#include <hip/hip_bf16.h>
#include <math.h>

typedef __attribute__((ext_vector_type(8))) short bf16x8;
typedef __attribute__((ext_vector_type(4))) float f32x4;

#define N_B  2
#define CIN  128
#define COUT 128
#define T_   16
#define H_   64
#define W_   64
#define FANIN 3456

// ---- workspace byte offsets ----
#define OFF_WMAX   0          // 128 f32
#define OFF_SMAX   512        // 2 f32
#define OFF_SNORM  1024       // 4096 f32
#define OFF_WSQ    20480      // 16384 f32
#define OFF_DEMOD  86016      // 4096 f32
#define OFF_APACK  102400     // 442368 ushort (884,736 B)  [tap27][c4][m8][lane64][j8]
#define OFF_XMT    2097152    // 16,777,216 ushort (33.55 MB) [n][t][h][w][cin] bf16

// ---------- prep kernels ----------
__global__ __launch_bounds__(256) void k_wmax(const float* __restrict__ w,
                                              float* __restrict__ wmax) {
    int o = blockIdx.x;
    const float* p = w + (size_t)o * FANIN;
    float m = 0.f;
    for (int i = threadIdx.x; i < FANIN; i += 256) m = fmaxf(m, fabsf(p[i]));
    __shared__ float red[256];
    red[threadIdx.x] = m; __syncthreads();
    for (int s = 128; s > 0; s >>= 1) {
        if (threadIdx.x < s) red[threadIdx.x] = fmaxf(red[threadIdx.x], red[threadIdx.x + s]);
        __syncthreads();
    }
    if (threadIdx.x == 0) wmax[o] = red[0];
}

__global__ __launch_bounds__(256) void k_smax(const float* __restrict__ s,
                                              float* __restrict__ smax) {
    int n = blockIdx.x;
    const float* p = s + (size_t)n * CIN * T_;
    float m = 0.f;
    for (int i = threadIdx.x; i < CIN * T_; i += 256) m = fmaxf(m, fabsf(p[i]));
    __shared__ float red[256];
    red[threadIdx.x] = m; __syncthreads();
    for (int q = 128; q > 0; q >>= 1) {
        if (threadIdx.x < q) red[threadIdx.x] = fmaxf(red[threadIdx.x], red[threadIdx.x + q]);
        __syncthreads();
    }
    if (threadIdx.x == 0) smax[n] = red[0];
}

__global__ __launch_bounds__(256) void k_snorm(const float* __restrict__ style,
                                               const float* __restrict__ smax,
                                               float* __restrict__ snorm) {
    int idx = blockIdx.x * 256 + threadIdx.x;
    if (idx < N_B * CIN * T_) {
        int n = idx / (CIN * T_);
        snorm[idx] = style[idx] / smax[n];
    }
}

// normalize weight (fp32), pack bf16 into MFMA A-frag order, compute wsq[o][i]
__global__ __launch_bounds__(128) void k_wpack(const float* __restrict__ w,
                                               const float* __restrict__ wmax,
                                               ushort* __restrict__ apack,
                                               float* __restrict__ wsq) {
    int o = blockIdx.x, i = threadIdx.x;
    float inv = 1.0f / (wmax[o] * sqrtf((float)FANIN));
    const float* p = w + ((size_t)o * CIN + i) * 27;
    int c = i >> 5, ii = i & 31;
    int lane = (o & 15) + ((ii >> 3) << 4);   // A: row=l&15, k=(l>>4)*8+j
    int j = ii & 7;
    int m = o >> 4;
    size_t base = (((size_t)c * 8 + m) * 64 + lane) * 8 + j;
    float sq = 0.f;
    #pragma unroll
    for (int tap = 0; tap < 27; tap++) {
        float wn = p[tap] * inv;
        sq = fmaf(wn, wn, sq);
        __hip_bfloat16 hb = __float2bfloat16(wn);
        apack[base + (size_t)tap * 16384] = *(ushort*)&hb;
    }
    wsq[o * CIN + i] = sq;
}

__global__ __launch_bounds__(128) void k_demod(const float* __restrict__ wsq,
                                               const float* __restrict__ snorm,
                                               float* __restrict__ demod) {
    int nt = blockIdx.x;
    int n = nt / T_, t = nt % T_;
    __shared__ float s2[CIN];
    int tid = threadIdx.x;
    float sv = snorm[(n * CIN + tid) * T_ + t];
    s2[tid] = sv * sv;
    __syncthreads();
    const float* wq = wsq + tid * CIN;   // o = tid
    float d = 0.f;
    for (int i = 0; i < CIN; i++) d = fmaf(wq[i], s2[i], d);
    demod[(n * COUT + tid) * T_ + t] = 1.0f / sqrtf(d + 1e-8f);
}

// transpose x -> xmt[n][t][h][w][cin] bf16, style-modulated
__global__ __launch_bounds__(256) void k_xmt(const float* __restrict__ x,
                                             const float* __restrict__ snorm,
                                             ushort* __restrict__ xmt) {
    __shared__ float lds[CIN * 65];
    int bid = blockIdx.x;
    int h = bid & 63, t = (bid >> 6) & 15, n = bid >> 10;
    int tid = threadIdx.x;
    int wl = tid & 63, cq = tid >> 6;
    for (int pass = 0; pass < 32; pass++) {
        int ci = pass * 4 + cq;
        float s = snorm[(n * CIN + ci) * T_ + t];
        float v = x[(((size_t)(n * CIN + ci) * T_ + t) * H_ + h) * W_ + wl] * s;
        lds[ci * 65 + wl] = v;
    }
    __syncthreads();
    int ci2 = tid & 63, wq = tid >> 6;
    uint* dst = (uint*)xmt;
    for (int pass = 0; pass < 16; pass++) {
        int w = pass * 4 + wq;
        float f0 = lds[(2 * ci2) * 65 + w];
        float f1 = lds[(2 * ci2 + 1) * 65 + w];
        __hip_bfloat16 h0 = __float2bfloat16(f0);
        __hip_bfloat16 h1 = __float2bfloat16(f1);
        uint pk = (uint)(*(ushort*)&h0) | ((uint)(*(ushort*)&h1) << 16);
        dst[((((size_t)(n * T_ + t) * H_ + h) * W_ + w)) * 64 + ci2] = pk;
    }
}

// ---------- main MFMA conv ----------
// grid: 1024 blocks = n(2) * t(16) * h2(32); block = 256 thr = 4 waves
// block tile: 128 Cout x (2h x 64w); wave: 64 Cout x (1h x 64w)
// A-operand ping-pong pipeline (R6) + 3 blocks/CU via launch_bounds(256,3):
// independent blocks cover each other's stage windows (TLP, not ILP).
__global__ __launch_bounds__(256, 3) void k_conv(const ushort* __restrict__ xmt,
                                                 const ushort* __restrict__ apack,
                                                 const float* __restrict__ demod,
                                                 const float* __restrict__ bias,
                                                 float* __restrict__ out) {
    // xs[t'3][h'4][g4][w66] granules of 8 bf16 (16B); 50688 B -> 3 blocks/CU
    __shared__ ushort __attribute__((aligned(16))) xs[25344];

    int bid = blockIdx.x;
    int h2 = bid & 31, t = (bid >> 5) & 15, n = bid >> 9;
    int hbase = h2 * 2;
    int tid = threadIdx.x;
    int lane = tid & 63;
    int wid = tid >> 6;
    int mrow = wid & 1;    // cout half (64)
    int hrow = wid >> 1;   // h row (0/1)

    // ---- chunk-invariant staging offsets (13 granules/thread) ----
    uint goff[13];     // element offset into xmt (for chunk c add c*32)
    uint loff[13];     // byte offset into xs; 0xFFFFFFFF = no slot
    uint vmask = 0;    // bit k set -> in-bounds (load), clear -> zero-fill
    #pragma unroll
    for (int k = 0; k < 13; ++k) {
        int idx = tid + (k << 8);
        goff[k] = 0u;
        if (idx < 3168) {
            int g = idx & 3;
            int r = idx >> 2;
            int w = r % 66;
            int q = r / 66;
            int hh = q & 3, tz = q >> 2;
            int gt = t + tz - 1, gh = hbase + hh - 1, gw = w - 1;
            if ((unsigned)gt < T_ && (unsigned)gh < H_ && (unsigned)gw < W_) {
                goff[k] = (uint)((((n * T_ + gt) * H_ + gh) * W_ + gw) * CIN + g * 8);
                vmask |= (1u << k);
            }
            loff[k] = (uint)(((((tz * 4 + hh) * 4) + g) * 66 + w) * 16);
        } else {
            loff[k] = 0xFFFFFFFFu;
        }
    }

    f32x4 acc[4][4];
    #pragma unroll
    for (int i = 0; i < 4; i++)
        #pragma unroll
        for (int jn = 0; jn < 4; jn++)
            acc[i][jn] = (f32x4){0.f, 0.f, 0.f, 0.f};

    bf16x8 Abank0[12], Abank1[12];

#define LOADA(BANK, G) do { \
    const ushort* apg_ = apc + (G) * 3 * 16384; \
    _Pragma("unroll") \
    for (int dx_ = 0; dx_ < 3; ++dx_) { \
        _Pragma("unroll") \
        for (int mi_ = 0; mi_ < 4; ++mi_) \
            BANK[dx_ * 4 + mi_] = *(const bf16x8*)(apg_ + dx_ * 16384 + mi_ * 512); \
    } \
} while (0)

#define GROUPC(BANK, G) do { \
    const int tz_ = (G) / 3, dy_ = (G) % 3; \
    const ushort* bb_ = &xs[(((tz_ * 4 + hrow + dy_) * 4 + (lane >> 4)) * 66 + (lane & 15)) * 8]; \
    _Pragma("unroll") \
    for (int dx_ = 0; dx_ < 3; ++dx_) { \
        bf16x8 b0_ = *(const bf16x8*)(bb_ + dx_ * 8); \
        bf16x8 b1_ = *(const bf16x8*)(bb_ + dx_ * 8 + 128); \
        bf16x8 b2_ = *(const bf16x8*)(bb_ + dx_ * 8 + 256); \
        bf16x8 b3_ = *(const bf16x8*)(bb_ + dx_ * 8 + 384); \
        _Pragma("unroll") \
        for (int mi_ = 0; mi_ < 4; ++mi_) { \
            acc[mi_][0] = __builtin_amdgcn_mfma_f32_16x16x32_bf16(BANK[dx_*4+mi_], b0_, acc[mi_][0], 0, 0, 0); \
            acc[mi_][1] = __builtin_amdgcn_mfma_f32_16x16x32_bf16(BANK[dx_*4+mi_], b1_, acc[mi_][1], 0, 0, 0); \
            acc[mi_][2] = __builtin_amdgcn_mfma_f32_16x16x32_bf16(BANK[dx_*4+mi_], b2_, acc[mi_][2], 0, 0, 0); \
            acc[mi_][3] = __builtin_amdgcn_mfma_f32_16x16x32_bf16(BANK[dx_*4+mi_], b3_, acc[mi_][3], 0, 0, 0); \
        } \
    } \
} while (0)

    for (int c = 0; c < 4; ++c) {     // cin chunks of 32
        __syncthreads();   // waves done reading previous chunk
        // serial stage of chunk c: 13 loads then 13 ds_writes
        {
            uint4 pv[13];
            #pragma unroll
            for (int k = 0; k < 13; ++k) {
                uint4 v = make_uint4(0u, 0u, 0u, 0u);
                if ((vmask >> k) & 1u) v = *(const uint4*)(xmt + goff[k] + c * 32);
                pv[k] = v;
            }
            #pragma unroll
            for (int k = 0; k < 13; ++k)
                if (loff[k] != 0xFFFFFFFFu) *(uint4*)((char*)&xs[0] + loff[k]) = pv[k];
        }
        __syncthreads();

        const ushort* apc = apack + (c * 4096 + mrow * 2048 + lane * 8);

        LOADA(Abank0, 0);
        LOADA(Abank1, 1); __builtin_amdgcn_sched_barrier(0); GROUPC(Abank0, 0);
        LOADA(Abank0, 2); __builtin_amdgcn_sched_barrier(0); GROUPC(Abank1, 1);
        LOADA(Abank1, 3); __builtin_amdgcn_sched_barrier(0); GROUPC(Abank0, 2);
        LOADA(Abank0, 4); __builtin_amdgcn_sched_barrier(0); GROUPC(Abank1, 3);
        LOADA(Abank1, 5); __builtin_amdgcn_sched_barrier(0); GROUPC(Abank0, 4);
        LOADA(Abank0, 6); __builtin_amdgcn_sched_barrier(0); GROUPC(Abank1, 5);
        LOADA(Abank1, 7); __builtin_amdgcn_sched_barrier(0); GROUPC(Abank0, 6);
        LOADA(Abank0, 8); __builtin_amdgcn_sched_barrier(0); GROUPC(Abank1, 7);
        GROUPC(Abank0, 8);
    }
#undef LOADA
#undef GROUPC

    // epilogue: C layout col=lane&15 (w), row=(lane>>4)*4+reg (cout)
    int h = hbase + hrow;
    #pragma unroll
    for (int mi = 0; mi < 4; mi++) {
        #pragma unroll
        for (int r = 0; r < 4; r++) {
            int o = mrow * 64 + mi * 16 + (lane >> 4) * 4 + r;
            float d = demod[(n * COUT + o) * T_ + t];
            float bv = bias[o];
            #pragma unroll
            for (int nb = 0; nb < 4; nb++) {
                float z = fmaf(acc[mi][nb][r], d, bv);
                z = (z >= 0.f ? z : 0.2f * z) * 1.41421356237309515f;
                out[(((size_t)(n * COUT + o) * T_ + t) * H_ + h) * W_ + nb * 16 + (lane & 15)] = z;
            }
        }
    }
}

extern "C" void kernel_launch(void* const* d_in, const int* in_sizes, int n_in,
                              void* d_out, int out_size, void* d_ws, size_t ws_size,
                              hipStream_t stream) {
    const float* x      = (const float*)d_in[0];
    const float* weight = (const float*)d_in[1];
    const float* style  = (const float*)d_in[2];
    const float* bias   = (const float*)d_in[3];
    float* out = (float*)d_out;

    char* ws = (char*)d_ws;
    float*  wmax  = (float*)(ws + OFF_WMAX);
    float*  smax  = (float*)(ws + OFF_SMAX);
    float*  snorm = (float*)(ws + OFF_SNORM);
    float*  wsq   = (float*)(ws + OFF_WSQ);
    float*  demod = (float*)(ws + OFF_DEMOD);
    ushort* apack = (ushort*)(ws + OFF_APACK);
    ushort* xmt   = (ushort*)(ws + OFF_XMT);

    k_wmax <<<COUT, 256, 0, stream>>>(weight, wmax);
    k_smax <<<N_B, 256, 0, stream>>>(style, smax);
    k_snorm<<<(N_B * CIN * T_ + 255) / 256, 256, 0, stream>>>(style, smax, snorm);
    k_wpack<<<COUT, 128, 0, stream>>>(weight, wmax, apack, wsq);
    k_demod<<<N_B * T_, 128, 0, stream>>>(wsq, snorm, demod);
    k_xmt  <<<N_B * T_ * H_, 256, 0, stream>>>(x, snorm, xmt);

    k_conv<<<N_B * T_ * (H_ / 2), 256, 0, stream>>>(xmt, apack, demod, bias, out);
}

// Round 11
// 149.636 us; speedup vs baseline: 1.8884x; 1.8546x over previous
//
#include <hip/hip_runtime.h>
#include <hip/hip_bf16.h>
#include <math.h>

typedef __attribute__((ext_vector_type(8))) short bf16x8;
typedef __attribute__((ext_vector_type(4))) float f32x4;

#define N_B  2
#define CIN  128
#define COUT 128
#define T_   16
#define H_   64
#define W_   64
#define FANIN 3456

// ---- workspace byte offsets ----
#define OFF_WMAX   0          // 128 f32
#define OFF_SMAX   512        // 2 f32
#define OFF_SNORM  1024       // 4096 f32
#define OFF_WSQ    20480      // 16384 f32
#define OFF_DEMOD  86016      // 4096 f32
#define OFF_APACK  102400     // 442368 ushort (884,736 B)  [tap27][c4][m8][lane64][j8]
#define OFF_ZERO   1048576    // 16384 B zero page (below xmt)
#define OFF_XMT    2097152    // 16,777,216 ushort (33.55 MB) [n][t][h][w][cin] bf16
#define ZOFF       (-524288)  // (OFF_ZERO-OFF_XMT)/2 : zero page as ushort offset from xmt

// ---------- prep kernels ----------
__global__ __launch_bounds__(256) void k_zero(uint4* __restrict__ zp) {
    #pragma unroll
    for (int k = 0; k < 4; ++k)
        zp[threadIdx.x + k * 256] = make_uint4(0u, 0u, 0u, 0u);
}

__global__ __launch_bounds__(256) void k_wmax(const float* __restrict__ w,
                                              float* __restrict__ wmax) {
    int o = blockIdx.x;
    const float* p = w + (size_t)o * FANIN;
    float m = 0.f;
    for (int i = threadIdx.x; i < FANIN; i += 256) m = fmaxf(m, fabsf(p[i]));
    __shared__ float red[256];
    red[threadIdx.x] = m; __syncthreads();
    for (int s = 128; s > 0; s >>= 1) {
        if (threadIdx.x < s) red[threadIdx.x] = fmaxf(red[threadIdx.x], red[threadIdx.x + s]);
        __syncthreads();
    }
    if (threadIdx.x == 0) wmax[o] = red[0];
}

__global__ __launch_bounds__(256) void k_smax(const float* __restrict__ s,
                                              float* __restrict__ smax) {
    int n = blockIdx.x;
    const float* p = s + (size_t)n * CIN * T_;
    float m = 0.f;
    for (int i = threadIdx.x; i < CIN * T_; i += 256) m = fmaxf(m, fabsf(p[i]));
    __shared__ float red[256];
    red[threadIdx.x] = m; __syncthreads();
    for (int q = 128; q > 0; q >>= 1) {
        if (threadIdx.x < q) red[threadIdx.x] = fmaxf(red[threadIdx.x], red[threadIdx.x + q]);
        __syncthreads();
    }
    if (threadIdx.x == 0) smax[n] = red[0];
}

__global__ __launch_bounds__(256) void k_snorm(const float* __restrict__ style,
                                               const float* __restrict__ smax,
                                               float* __restrict__ snorm) {
    int idx = blockIdx.x * 256 + threadIdx.x;
    if (idx < N_B * CIN * T_) {
        int n = idx / (CIN * T_);
        snorm[idx] = style[idx] / smax[n];
    }
}

// normalize weight (fp32), pack bf16 into MFMA A-frag order, compute wsq[o][i]
__global__ __launch_bounds__(128) void k_wpack(const float* __restrict__ w,
                                               const float* __restrict__ wmax,
                                               ushort* __restrict__ apack,
                                               float* __restrict__ wsq) {
    int o = blockIdx.x, i = threadIdx.x;
    float inv = 1.0f / (wmax[o] * sqrtf((float)FANIN));
    const float* p = w + ((size_t)o * CIN + i) * 27;
    int c = i >> 5, ii = i & 31;
    int lane = (o & 15) + ((ii >> 3) << 4);   // A: row=l&15, k=(l>>4)*8+j
    int j = ii & 7;
    int m = o >> 4;
    size_t base = (((size_t)c * 8 + m) * 64 + lane) * 8 + j;
    float sq = 0.f;
    #pragma unroll
    for (int tap = 0; tap < 27; tap++) {
        float wn = p[tap] * inv;
        sq = fmaf(wn, wn, sq);
        __hip_bfloat16 hb = __float2bfloat16(wn);
        apack[base + (size_t)tap * 16384] = *(ushort*)&hb;
    }
    wsq[o * CIN + i] = sq;
}

__global__ __launch_bounds__(128) void k_demod(const float* __restrict__ wsq,
                                               const float* __restrict__ snorm,
                                               float* __restrict__ demod) {
    int nt = blockIdx.x;
    int n = nt / T_, t = nt % T_;
    __shared__ float s2[CIN];
    int tid = threadIdx.x;
    float sv = snorm[(n * CIN + tid) * T_ + t];
    s2[tid] = sv * sv;
    __syncthreads();
    const float* wq = wsq + tid * CIN;   // o = tid
    float d = 0.f;
    for (int i = 0; i < CIN; i++) d = fmaf(wq[i], s2[i], d);
    demod[(n * COUT + tid) * T_ + t] = 1.0f / sqrtf(d + 1e-8f);
}

// transpose x -> xmt[n][t][h][w][cin] bf16, style-modulated
__global__ __launch_bounds__(256) void k_xmt(const float* __restrict__ x,
                                             const float* __restrict__ snorm,
                                             ushort* __restrict__ xmt) {
    __shared__ float lds[CIN * 65];
    int bid = blockIdx.x;
    int h = bid & 63, t = (bid >> 6) & 15, n = bid >> 10;
    int tid = threadIdx.x;
    int wl = tid & 63, cq = tid >> 6;
    for (int pass = 0; pass < 32; pass++) {
        int ci = pass * 4 + cq;
        float s = snorm[(n * CIN + ci) * T_ + t];
        float v = x[(((size_t)(n * CIN + ci) * T_ + t) * H_ + h) * W_ + wl] * s;
        lds[ci * 65 + wl] = v;
    }
    __syncthreads();
    int ci2 = tid & 63, wq = tid >> 6;
    uint* dst = (uint*)xmt;
    for (int pass = 0; pass < 16; pass++) {
        int w = pass * 4 + wq;
        float f0 = lds[(2 * ci2) * 65 + w];
        float f1 = lds[(2 * ci2 + 1) * 65 + w];
        __hip_bfloat16 h0 = __float2bfloat16(f0);
        __hip_bfloat16 h1 = __float2bfloat16(f1);
        uint pk = (uint)(*(ushort*)&h0) | ((uint)(*(ushort*)&h1) << 16);
        dst[((((size_t)(n * T_ + t) * H_ + h) * W_ + w)) * 64 + ci2] = pk;
    }
}

// ---------- main MFMA conv ----------
// grid: 512 blocks = n(2)*t(16)*h4(16); block = 512 thr = 8 waves; 1 block/CU.
// block tile: 128 Cout x (4h x 64w); wave: 64 Cout x (1h x 64w).
// Staging: global_load_lds DOUBLE-BUFFER — issue chunk c+1's glds at the top
// of chunk c's compute (~2100 cyc MFMA cover); the end-of-chunk syncthreads'
// vmcnt(0) is then free. All-lane convergent issue; OOB/pad lanes read the
// zero page (per-lane global addr OK; LDS dest stays linear in tid).
// LDS layout per buffer: [q18][g4][w66] granules of 16B (w innermost in tid).
__global__ __launch_bounds__(512, 2) void k_conv(const ushort* __restrict__ xmt,
                                                 const ushort* __restrict__ apack,
                                                 const float* __restrict__ demod,
                                                 const float* __restrict__ bias,
                                                 float* __restrict__ out) {
    // 2 buffers x 4800 granules (4752 used + 48 pad) x 16B = 153,600 B
    __shared__ ushort __attribute__((aligned(16))) xs[76800];

    int bid = blockIdx.x;
    int h4 = bid & 15, t = (bid >> 4) & 15, n = bid >> 8;
    int hbase = h4 * 4;
    int tid = threadIdx.x;
    int lane = tid & 63;
    int wid = tid >> 6;
    int mrow = wid & 1;    // cout half (64)
    int hq = wid >> 1;     // h row 0..3
    int lw = lane & 15, lg = lane >> 4;

    // ---- chunk-invariant staging source offsets (10 slots; [q][g][w] order) ----
    int goff[10];
    #pragma unroll
    for (int k = 0; k < 10; ++k) {
        int idx = tid + (k << 9);
        int off = ZOFF;
        if (idx < 4752) {
            int w  = idx % 66;
            int gq = idx / 66;
            int g  = gq & 3;
            int q  = gq >> 2;
            int hh = q % 6, tz = q / 6;
            int gt = t + tz - 1, gh = hbase + hh - 1, gw = w - 1;
            if ((unsigned)gt < T_ && (unsigned)gh < H_ && (unsigned)gw < W_)
                off = (((n * 16 + gt) * 64 + gh) * 64 + gw) * 128 + g * 8;
        }
        goff[k] = off;
    }

#define STAGE(cc, dbuf) do { \
    _Pragma("unroll") \
    for (int k = 0; k < 9; ++k) \
        __builtin_amdgcn_global_load_lds( \
            (const __attribute__((address_space(1))) void*)(xmt + goff[k] + (cc) * 32), \
            (__attribute__((address_space(3))) void*)((char*)xs + (size_t)(dbuf) * 76800 \
                                                      + ((size_t)tid + (k << 9)) * 16), \
            16, 0, 0); \
    if (wid < 3) \
        __builtin_amdgcn_global_load_lds( \
            (const __attribute__((address_space(1))) void*)(xmt + goff[9] + (cc) * 32), \
            (__attribute__((address_space(3))) void*)((char*)xs + (size_t)(dbuf) * 76800 \
                                                      + ((size_t)tid + (9 << 9)) * 16), \
            16, 0, 0); \
} while (0)

    f32x4 acc[4][4];
    #pragma unroll
    for (int i = 0; i < 4; i++)
        #pragma unroll
        for (int jn = 0; jn < 4; jn++)
            acc[i][jn] = (f32x4){0.f, 0.f, 0.f, 0.f};

    bf16x8 Abank0[12], Abank1[12];

#define LOADA(BANK, G) do { \
    const ushort* apg_ = apc + (G) * 3 * 16384; \
    _Pragma("unroll") \
    for (int dx_ = 0; dx_ < 3; ++dx_) { \
        _Pragma("unroll") \
        for (int mi_ = 0; mi_ < 4; ++mi_) \
            BANK[dx_ * 4 + mi_] = *(const bf16x8*)(apg_ + dx_ * 16384 + mi_ * 512); \
    } \
} while (0)

#define GROUPC(BANK, G) do { \
    const int q_ = ((G) / 3) * 6 + hq + ((G) % 3); \
    const ushort* bb_ = &xsb[((q_ * 4 + lg) * 66 + lw) * 8]; \
    _Pragma("unroll") \
    for (int dx_ = 0; dx_ < 3; ++dx_) { \
        bf16x8 b0_ = *(const bf16x8*)(bb_ + dx_ * 8); \
        bf16x8 b1_ = *(const bf16x8*)(bb_ + dx_ * 8 + 128); \
        bf16x8 b2_ = *(const bf16x8*)(bb_ + dx_ * 8 + 256); \
        bf16x8 b3_ = *(const bf16x8*)(bb_ + dx_ * 8 + 384); \
        _Pragma("unroll") \
        for (int mi_ = 0; mi_ < 4; ++mi_) { \
            acc[mi_][0] = __builtin_amdgcn_mfma_f32_16x16x32_bf16(BANK[dx_*4+mi_], b0_, acc[mi_][0], 0, 0, 0); \
            acc[mi_][1] = __builtin_amdgcn_mfma_f32_16x16x32_bf16(BANK[dx_*4+mi_], b1_, acc[mi_][1], 0, 0, 0); \
            acc[mi_][2] = __builtin_amdgcn_mfma_f32_16x16x32_bf16(BANK[dx_*4+mi_], b2_, acc[mi_][2], 0, 0, 0); \
            acc[mi_][3] = __builtin_amdgcn_mfma_f32_16x16x32_bf16(BANK[dx_*4+mi_], b3_, acc[mi_][3], 0, 0, 0); \
        } \
    } \
} while (0)

    // prologue: stage chunk 0 into buffer 0
    STAGE(0, 0);
    __syncthreads();   // vmcnt(0) drains glds; buffer 0 ready

    for (int c = 0; c < 4; ++c) {     // cin chunks of 32
        int buf = c & 1;
        if (c < 3) STAGE(c + 1, buf ^ 1);   // overlapped with this chunk's MFMAs
        __builtin_amdgcn_sched_barrier(0);  // keep the glds issue up top

        const ushort* apc = apack + (c * 4096 + mrow * 2048 + lane * 8);
        const ushort* xsb = xs + buf * 38400;

        LOADA(Abank0, 0);
        LOADA(Abank1, 1); __builtin_amdgcn_sched_barrier(0); GROUPC(Abank0, 0);
        LOADA(Abank0, 2); __builtin_amdgcn_sched_barrier(0); GROUPC(Abank1, 1);
        LOADA(Abank1, 3); __builtin_amdgcn_sched_barrier(0); GROUPC(Abank0, 2);
        LOADA(Abank0, 4); __builtin_amdgcn_sched_barrier(0); GROUPC(Abank1, 3);
        LOADA(Abank1, 5); __builtin_amdgcn_sched_barrier(0); GROUPC(Abank0, 4);
        LOADA(Abank0, 6); __builtin_amdgcn_sched_barrier(0); GROUPC(Abank1, 5);
        LOADA(Abank1, 7); __builtin_amdgcn_sched_barrier(0); GROUPC(Abank0, 6);
        LOADA(Abank0, 8); __builtin_amdgcn_sched_barrier(0); GROUPC(Abank1, 7);
        GROUPC(Abank0, 8);

        __syncthreads();   // waves done reading buf; vmcnt(0) -> buf^1 complete
    }
#undef LOADA
#undef GROUPC
#undef STAGE

    // epilogue: C layout col=lane&15 (w), row=(lane>>4)*4+reg (cout)
    int h = hbase + hq;
    #pragma unroll
    for (int mi = 0; mi < 4; mi++) {
        #pragma unroll
        for (int r = 0; r < 4; r++) {
            int o = mrow * 64 + mi * 16 + lg * 4 + r;
            float d = demod[(n * COUT + o) * T_ + t];
            float bv = bias[o];
            #pragma unroll
            for (int nb = 0; nb < 4; nb++) {
                float z = fmaf(acc[mi][nb][r], d, bv);
                z = (z >= 0.f ? z : 0.2f * z) * 1.41421356237309515f;
                out[(((size_t)(n * COUT + o) * T_ + t) * H_ + h) * W_ + nb * 16 + lw] = z;
            }
        }
    }
}

extern "C" void kernel_launch(void* const* d_in, const int* in_sizes, int n_in,
                              void* d_out, int out_size, void* d_ws, size_t ws_size,
                              hipStream_t stream) {
    const float* x      = (const float*)d_in[0];
    const float* weight = (const float*)d_in[1];
    const float* style  = (const float*)d_in[2];
    const float* bias   = (const float*)d_in[3];
    float* out = (float*)d_out;

    char* ws = (char*)d_ws;
    float*  wmax  = (float*)(ws + OFF_WMAX);
    float*  smax  = (float*)(ws + OFF_SMAX);
    float*  snorm = (float*)(ws + OFF_SNORM);
    float*  wsq   = (float*)(ws + OFF_WSQ);
    float*  demod = (float*)(ws + OFF_DEMOD);
    uint4*  zpage = (uint4*)(ws + OFF_ZERO);
    ushort* apack = (ushort*)(ws + OFF_APACK);
    ushort* xmt   = (ushort*)(ws + OFF_XMT);

    k_zero <<<1, 256, 0, stream>>>(zpage);
    k_wmax <<<COUT, 256, 0, stream>>>(weight, wmax);
    k_smax <<<N_B, 256, 0, stream>>>(style, smax);
    k_snorm<<<(N_B * CIN * T_ + 255) / 256, 256, 0, stream>>>(style, smax, snorm);
    k_wpack<<<COUT, 128, 0, stream>>>(weight, wmax, apack, wsq);
    k_demod<<<N_B * T_, 128, 0, stream>>>(wsq, snorm, demod);
    k_xmt  <<<N_B * T_ * H_, 256, 0, stream>>>(x, snorm, xmt);

    k_conv<<<N_B * T_ * (H_ / 4), 512, 0, stream>>>(xmt, apack, demod, bias, out);
}

// Round 12
// 147.126 us; speedup vs baseline: 1.9207x; 1.0171x over previous
//
#include <hip/hip_runtime.h>
#include <hip/hip_bf16.h>
#include <math.h>

typedef __attribute__((ext_vector_type(8))) short bf16x8;
typedef __attribute__((ext_vector_type(4))) float f32x4;

#define N_B  2
#define CIN  128
#define COUT 128
#define T_   16
#define H_   64
#define W_   64
#define FANIN 3456

// ---- workspace byte offsets ----
#define OFF_WMAX   0          // 128 f32
#define OFF_SMAX   512        // 2 f32
#define OFF_SNORM  1024       // 4096 f32
#define OFF_WSQ    20480      // 16384 f32
#define OFF_DEMOD  86016      // 4096 f32
#define OFF_APACK  102400     // 442368 ushort (884,736 B)  [tap27][c4][m8][lane64][j8]
#define OFF_ZERO   1048576    // 16384 B zero page (below xmt)
#define OFF_XMT    2097152    // 16,777,216 ushort (33.55 MB) [n][t][h][w][cin] bf16
#define ZOFF       (-524288)  // (OFF_ZERO-OFF_XMT)/2 : zero page as ushort offset from xmt

// ---------- prep kernels ----------
__global__ __launch_bounds__(256) void k_zero(uint4* __restrict__ zp) {
    #pragma unroll
    for (int k = 0; k < 4; ++k)
        zp[threadIdx.x + k * 256] = make_uint4(0u, 0u, 0u, 0u);
}

__global__ __launch_bounds__(256) void k_wmax(const float* __restrict__ w,
                                              float* __restrict__ wmax) {
    int o = blockIdx.x;
    const float* p = w + (size_t)o * FANIN;
    float m = 0.f;
    for (int i = threadIdx.x; i < FANIN; i += 256) m = fmaxf(m, fabsf(p[i]));
    __shared__ float red[256];
    red[threadIdx.x] = m; __syncthreads();
    for (int s = 128; s > 0; s >>= 1) {
        if (threadIdx.x < s) red[threadIdx.x] = fmaxf(red[threadIdx.x], red[threadIdx.x + s]);
        __syncthreads();
    }
    if (threadIdx.x == 0) wmax[o] = red[0];
}

__global__ __launch_bounds__(256) void k_smax(const float* __restrict__ s,
                                              float* __restrict__ smax) {
    int n = blockIdx.x;
    const float* p = s + (size_t)n * CIN * T_;
    float m = 0.f;
    for (int i = threadIdx.x; i < CIN * T_; i += 256) m = fmaxf(m, fabsf(p[i]));
    __shared__ float red[256];
    red[threadIdx.x] = m; __syncthreads();
    for (int q = 128; q > 0; q >>= 1) {
        if (threadIdx.x < q) red[threadIdx.x] = fmaxf(red[threadIdx.x], red[threadIdx.x + q]);
        __syncthreads();
    }
    if (threadIdx.x == 0) smax[n] = red[0];
}

__global__ __launch_bounds__(256) void k_snorm(const float* __restrict__ style,
                                               const float* __restrict__ smax,
                                               float* __restrict__ snorm) {
    int idx = blockIdx.x * 256 + threadIdx.x;
    if (idx < N_B * CIN * T_) {
        int n = idx / (CIN * T_);
        snorm[idx] = style[idx] / smax[n];
    }
}

// normalize weight (fp32), pack bf16 into MFMA A-frag order, compute wsq[o][i]
__global__ __launch_bounds__(128) void k_wpack(const float* __restrict__ w,
                                               const float* __restrict__ wmax,
                                               ushort* __restrict__ apack,
                                               float* __restrict__ wsq) {
    int o = blockIdx.x, i = threadIdx.x;
    float inv = 1.0f / (wmax[o] * sqrtf((float)FANIN));
    const float* p = w + ((size_t)o * CIN + i) * 27;
    int c = i >> 5, ii = i & 31;
    int lane = (o & 15) + ((ii >> 3) << 4);   // A: row=l&15, k=(l>>4)*8+j
    int j = ii & 7;
    int m = o >> 4;
    size_t base = (((size_t)c * 8 + m) * 64 + lane) * 8 + j;
    float sq = 0.f;
    #pragma unroll
    for (int tap = 0; tap < 27; tap++) {
        float wn = p[tap] * inv;
        sq = fmaf(wn, wn, sq);
        __hip_bfloat16 hb = __float2bfloat16(wn);
        apack[base + (size_t)tap * 16384] = *(ushort*)&hb;
    }
    wsq[o * CIN + i] = sq;
}

__global__ __launch_bounds__(128) void k_demod(const float* __restrict__ wsq,
                                               const float* __restrict__ snorm,
                                               float* __restrict__ demod) {
    int nt = blockIdx.x;
    int n = nt / T_, t = nt % T_;
    __shared__ float s2[CIN];
    int tid = threadIdx.x;
    float sv = snorm[(n * CIN + tid) * T_ + t];
    s2[tid] = sv * sv;
    __syncthreads();
    const float* wq = wsq + tid * CIN;   // o = tid
    float d = 0.f;
    for (int i = 0; i < CIN; i++) d = fmaf(wq[i], s2[i], d);
    demod[(n * COUT + tid) * T_ + t] = 1.0f / sqrtf(d + 1e-8f);
}

// transpose x -> xmt[n][t][h][w][cin] bf16, style-modulated
__global__ __launch_bounds__(256) void k_xmt(const float* __restrict__ x,
                                             const float* __restrict__ snorm,
                                             ushort* __restrict__ xmt) {
    __shared__ float lds[CIN * 65];
    int bid = blockIdx.x;
    int h = bid & 63, t = (bid >> 6) & 15, n = bid >> 10;
    int tid = threadIdx.x;
    int wl = tid & 63, cq = tid >> 6;
    for (int pass = 0; pass < 32; pass++) {
        int ci = pass * 4 + cq;
        float s = snorm[(n * CIN + ci) * T_ + t];
        float v = x[(((size_t)(n * CIN + ci) * T_ + t) * H_ + h) * W_ + wl] * s;
        lds[ci * 65 + wl] = v;
    }
    __syncthreads();
    int ci2 = tid & 63, wq = tid >> 6;
    uint* dst = (uint*)xmt;
    for (int pass = 0; pass < 16; pass++) {
        int w = pass * 4 + wq;
        float f0 = lds[(2 * ci2) * 65 + w];
        float f1 = lds[(2 * ci2 + 1) * 65 + w];
        __hip_bfloat16 h0 = __float2bfloat16(f0);
        __hip_bfloat16 h1 = __float2bfloat16(f1);
        uint pk = (uint)(*(ushort*)&h0) | ((uint)(*(ushort*)&h1) << 16);
        dst[((((size_t)(n * T_ + t) * H_ + h) * W_ + w)) * 64 + ci2] = pk;
    }
}

// ---------- main MFMA conv ----------
// grid: 256 blocks = n(2)*t(16)*h8(8) -> exactly 1 block/CU, no tail.
// block = 512 thr = 8 waves = 2 mrow x 4 hp; wave tile: 64 Cout x 2h x 64w,
// acc[4][8] (128 VGPR). Per tap: 4 A-frags + 8 ds_read_b128 -> 32 MFMA
// (A amortization 8:1). Tap-level A ping-pong (banks = 2x16 VGPR only).
// Staging: convergent glds (zero regs) into one 128 KiB buffer, serial per
// chunk (~2-3% of wall); OOB/pad lanes read the zero page.
// LDS: [q30 (tz3*h10)][g4][w66] granules of 16B, + pad to 8192 granules.
__global__ __launch_bounds__(512, 2) void k_conv(const ushort* __restrict__ xmt,
                                                 const ushort* __restrict__ apack,
                                                 const float* __restrict__ demod,
                                                 const float* __restrict__ bias,
                                                 float* __restrict__ out) {
    __shared__ ushort __attribute__((aligned(16))) xs[65536];   // 131,072 B

    int bid = blockIdx.x;
    int h8 = bid & 7, t = (bid >> 3) & 15, n = bid >> 7;
    int hbase = h8 * 8;
    int tid = threadIdx.x;
    int lane = tid & 63;
    int wid = tid >> 6;
    int mrow = wid & 1;    // cout half (64)
    int hp = wid >> 1;     // h pair 0..3 (rows hp*2, hp*2+1)
    int lw = lane & 15, lg = lane >> 4;

    // ---- chunk-invariant staging source offsets (16 slots, all convergent) ----
    int goff[16];
    #pragma unroll
    for (int k = 0; k < 16; ++k) {
        int idx = tid + (k << 9);
        int off = ZOFF;
        if (idx < 7920) {
            int w = idx % 66;
            int r = idx / 66;
            int g = r & 3;
            int q = r >> 2;           // q = tz*10 + hh
            int tz = q / 10, hh = q % 10;
            int gt = t + tz - 1, gh = hbase + hh - 1, gw = w - 1;
            if ((unsigned)gt < T_ && (unsigned)gh < H_ && (unsigned)gw < W_)
                off = (((n * 16 + gt) * 64 + gh) * 64 + gw) * 128 + g * 8;
        }
        goff[k] = off;
    }

#define STAGE(cc) do { \
    _Pragma("unroll") \
    for (int k = 0; k < 16; ++k) \
        __builtin_amdgcn_global_load_lds( \
            (const __attribute__((address_space(1))) void*)(xmt + goff[k] + (cc) * 32), \
            (__attribute__((address_space(3))) void*)((char*)xs + ((size_t)tid + (k << 9)) * 16), \
            16, 0, 0); \
} while (0)

    f32x4 acc[4][8];
    #pragma unroll
    for (int i = 0; i < 4; i++)
        #pragma unroll
        for (int jn = 0; jn < 8; jn++)
            acc[i][jn] = (f32x4){0.f, 0.f, 0.f, 0.f};

    bf16x8 A0[4], A1[4];

#define LOADA(BANK, TAP) do { \
    const ushort* ap_ = apc + (TAP) * 16384; \
    BANK[0] = *(const bf16x8*)(ap_); \
    BANK[1] = *(const bf16x8*)(ap_ + 512); \
    BANK[2] = *(const bf16x8*)(ap_ + 1024); \
    BANK[3] = *(const bf16x8*)(ap_ + 1536); \
} while (0)

// per tap: 8 B granules (2 h-rows x 4 ws) + 32 MFMA
#define TAPC(BANK, TAP) do { \
    const int tz_ = (TAP) / 9, dy_ = ((TAP) / 3) % 3, dx_ = (TAP) % 3; \
    const int q0_ = tz_ * 10 + dy_; \
    const ushort* br0_ = &xs[(((q0_ + hp * 2 + 0) * 4 + lg) * 66 + lw) * 8 + dx_ * 8]; \
    const ushort* br1_ = &xs[(((q0_ + hp * 2 + 1) * 4 + lg) * 66 + lw) * 8 + dx_ * 8]; \
    bf16x8 b00_ = *(const bf16x8*)(br0_); \
    bf16x8 b01_ = *(const bf16x8*)(br0_ + 128); \
    bf16x8 b02_ = *(const bf16x8*)(br0_ + 256); \
    bf16x8 b03_ = *(const bf16x8*)(br0_ + 384); \
    bf16x8 b10_ = *(const bf16x8*)(br1_); \
    bf16x8 b11_ = *(const bf16x8*)(br1_ + 128); \
    bf16x8 b12_ = *(const bf16x8*)(br1_ + 256); \
    bf16x8 b13_ = *(const bf16x8*)(br1_ + 384); \
    _Pragma("unroll") \
    for (int mi_ = 0; mi_ < 4; ++mi_) { \
        acc[mi_][0] = __builtin_amdgcn_mfma_f32_16x16x32_bf16(BANK[mi_], b00_, acc[mi_][0], 0, 0, 0); \
        acc[mi_][1] = __builtin_amdgcn_mfma_f32_16x16x32_bf16(BANK[mi_], b01_, acc[mi_][1], 0, 0, 0); \
        acc[mi_][2] = __builtin_amdgcn_mfma_f32_16x16x32_bf16(BANK[mi_], b02_, acc[mi_][2], 0, 0, 0); \
        acc[mi_][3] = __builtin_amdgcn_mfma_f32_16x16x32_bf16(BANK[mi_], b03_, acc[mi_][3], 0, 0, 0); \
        acc[mi_][4] = __builtin_amdgcn_mfma_f32_16x16x32_bf16(BANK[mi_], b10_, acc[mi_][4], 0, 0, 0); \
        acc[mi_][5] = __builtin_amdgcn_mfma_f32_16x16x32_bf16(BANK[mi_], b11_, acc[mi_][5], 0, 0, 0); \
        acc[mi_][6] = __builtin_amdgcn_mfma_f32_16x16x32_bf16(BANK[mi_], b12_, acc[mi_][6], 0, 0, 0); \
        acc[mi_][7] = __builtin_amdgcn_mfma_f32_16x16x32_bf16(BANK[mi_], b13_, acc[mi_][7], 0, 0, 0); \
    } \
} while (0)

#define UNIT(ULD, UCMP, TNEXT, TCUR) \
    LOADA(ULD, TNEXT); __builtin_amdgcn_sched_barrier(0); TAPC(UCMP, TCUR);

    for (int c = 0; c < 4; ++c) {     // cin chunks of 32
        if (c) __syncthreads();       // all waves done reading previous chunk
        STAGE(c);
        __syncthreads();              // vmcnt(0) drained; buffer ready

        const ushort* apc = apack + (c * 4096 + mrow * 2048 + lane * 8);

        LOADA(A0, 0);
        UNIT(A1, A0,  1,  0)  UNIT(A0, A1,  2,  1)  UNIT(A1, A0,  3,  2)
        UNIT(A0, A1,  4,  3)  UNIT(A1, A0,  5,  4)  UNIT(A0, A1,  6,  5)
        UNIT(A1, A0,  7,  6)  UNIT(A0, A1,  8,  7)  UNIT(A1, A0,  9,  8)
        UNIT(A0, A1, 10,  9)  UNIT(A1, A0, 11, 10)  UNIT(A0, A1, 12, 11)
        UNIT(A1, A0, 13, 12)  UNIT(A0, A1, 14, 13)  UNIT(A1, A0, 15, 14)
        UNIT(A0, A1, 16, 15)  UNIT(A1, A0, 17, 16)  UNIT(A0, A1, 18, 17)
        UNIT(A1, A0, 19, 18)  UNIT(A0, A1, 20, 19)  UNIT(A1, A0, 21, 20)
        UNIT(A0, A1, 22, 21)  UNIT(A1, A0, 23, 22)  UNIT(A0, A1, 24, 23)
        UNIT(A1, A0, 25, 24)  UNIT(A0, A1, 26, 25)
        TAPC(A0, 26);
    }
#undef UNIT
#undef LOADA
#undef TAPC
#undef STAGE

    // epilogue: C layout col=lane&15 (w), row=(lane>>4)*4+reg (cout)
    #pragma unroll
    for (int mi = 0; mi < 4; mi++) {
        #pragma unroll
        for (int r = 0; r < 4; r++) {
            int o = mrow * 64 + mi * 16 + lg * 4 + r;
            float d = demod[(n * COUT + o) * T_ + t];
            float bv = bias[o];
            #pragma unroll
            for (int rl = 0; rl < 2; rl++) {
                int h = hbase + hp * 2 + rl;
                #pragma unroll
                for (int ws = 0; ws < 4; ws++) {
                    float z = fmaf(acc[mi][rl * 4 + ws][r], d, bv);
                    z = (z >= 0.f ? z : 0.2f * z) * 1.41421356237309515f;
                    out[(((size_t)(n * COUT + o) * T_ + t) * H_ + h) * W_ + ws * 16 + lw] = z;
                }
            }
        }
    }
}

extern "C" void kernel_launch(void* const* d_in, const int* in_sizes, int n_in,
                              void* d_out, int out_size, void* d_ws, size_t ws_size,
                              hipStream_t stream) {
    const float* x      = (const float*)d_in[0];
    const float* weight = (const float*)d_in[1];
    const float* style  = (const float*)d_in[2];
    const float* bias   = (const float*)d_in[3];
    float* out = (float*)d_out;

    char* ws = (char*)d_ws;
    float*  wmax  = (float*)(ws + OFF_WMAX);
    float*  smax  = (float*)(ws + OFF_SMAX);
    float*  snorm = (float*)(ws + OFF_SNORM);
    float*  wsq   = (float*)(ws + OFF_WSQ);
    float*  demod = (float*)(ws + OFF_DEMOD);
    uint4*  zpage = (uint4*)(ws + OFF_ZERO);
    ushort* apack = (ushort*)(ws + OFF_APACK);
    ushort* xmt   = (ushort*)(ws + OFF_XMT);

    k_zero <<<1, 256, 0, stream>>>(zpage);
    k_wmax <<<COUT, 256, 0, stream>>>(weight, wmax);
    k_smax <<<N_B, 256, 0, stream>>>(style, smax);
    k_snorm<<<(N_B * CIN * T_ + 255) / 256, 256, 0, stream>>>(style, smax, snorm);
    k_wpack<<<COUT, 128, 0, stream>>>(weight, wmax, apack, wsq);
    k_demod<<<N_B * T_, 128, 0, stream>>>(wsq, snorm, demod);
    k_xmt  <<<N_B * T_ * H_, 256, 0, stream>>>(x, snorm, xmt);

    k_conv<<<N_B * T_ * (H_ / 8), 512, 0, stream>>>(xmt, apack, demod, bias, out);
}